// Round 2
// baseline (354.576 us; speedup 1.0000x reference)
//
#include <hip/hip_runtime.h>
#include <hip/hip_bf16.h>
#include <math.h>

#define B_ 32
#define T_ 2048
#define F_ 2048
#define H_ 1024
#define A_ 512

typedef __attribute__((ext_vector_type(8))) short short8;
typedef __attribute__((ext_vector_type(4))) float f32x4;

__device__ __forceinline__ unsigned short f2bf(float x) {
  union { float f; unsigned int u; } v; v.f = x;
  unsigned int r = v.u + 0x7FFFu + ((v.u >> 16) & 1u);
  return (unsigned short)(r >> 16);
}

#define GLOAD_LDS16(gp, lp) __builtin_amdgcn_global_load_lds( \
    (const __attribute__((address_space(1))) void*)(gp), \
    (__attribute__((address_space(3))) void*)(lp), 16, 0, 0)

#define SBAR   asm volatile("s_barrier" ::: "memory")
#define WAITV0 asm volatile("s_waitcnt vmcnt(0)" ::: "memory")
#define WAITL0 asm volatile("s_waitcnt lgkmcnt(0)" ::: "memory")
#define SCHEDB __builtin_amdgcn_sched_barrier(0)

// ---------------- kernel 1: W_a f32 -> bf16 ----------------
__global__ __launch_bounds__(256) void k_convert_wa(const float* __restrict__ wa,
                                                    unsigned short* __restrict__ out) {
  int i = (blockIdx.x * 256 + threadIdx.x) * 4;
  float4 v = *(const float4*)(wa + i);
  ushort4 o;
  o.x = f2bf(v.x); o.y = f2bf(v.y); o.z = f2bf(v.z); o.w = f2bf(v.w);
  *(ushort4*)(out + i) = o;
}

// ---------------- kernel 2: hcomb[b][a] = hidden[b]·W_h[a] + b_h[a] + b_a[a] ----------------
__global__ __launch_bounds__(256) void k_hproj(const float* __restrict__ hidden,
                                               const float* __restrict__ Wh,
                                               const float* __restrict__ bh,
                                               const float* __restrict__ ba,
                                               float* __restrict__ hcomb) {
  int gw = (blockIdx.x * 256 + threadIdx.x) >> 6;   // wave id 0..16383
  int lane = threadIdx.x & 63;
  int b = gw >> 9, a = gw & 511;
  const float* wr = Wh + a * H_;
  const float* hr = hidden + b * H_;
  float acc = 0.f;
  #pragma unroll
  for (int k = 0; k < H_; k += 256) {
    float4 wv = *(const float4*)(wr + k + lane * 4);
    float4 hv = *(const float4*)(hr + k + lane * 4);
    acc += wv.x * hv.x + wv.y * hv.y + wv.z * hv.z + wv.w * hv.w;
  }
  #pragma unroll
  for (int off = 32; off; off >>= 1) acc += __shfl_xor(acc, off);
  if (lane == 0) hcomb[gw] = acc + bh[a] + ba[a];
}

// ---------------- kernel 3: fused energy GEMM ----------------
// energy[m] = (sum_a tanh(hcomb[b][a] + feat[m]·W_a[a]) * v_w[a] + v_b) / sqrt(512)
// M=65536, K=2048, N=512 full per block. BM=64, BK=32, double-buffered LDS,
// raw s_barrier + vmcnt(0)-only drains (spill-robust counted discipline).
// LDS rows are 64 B; bank swizzle: pslot16 = (slot16 + (row>>1)) & 3 (add-rotate,
// 2-way residual = free; lane-uniform pslot -> ds_read offset immediates).
__global__ __launch_bounds__(512, 4) void k_energy(
    const float* __restrict__ feat, const unsigned short* __restrict__ wab,
    const float* __restrict__ hcomb, const float* __restrict__ vw,
    const float* __restrict__ vb, float* __restrict__ energy) {
  // layout: Bs 2x32768 | As 2x4096 @65536 | s_h @73728 | s_v @75776 | e_red @77824
  __shared__ __align__(16) char smem[78848];

  const int tid = threadIdx.x;
  const int lane = tid & 63;
  const int w = tid >> 6;
  const int wm = w >> 2, wn = w & 3;
  const int lrow = lane & 15, lk = lane >> 4;
  const int m0 = blockIdx.x * 64;
  const int bb = m0 >> 11;

  float* s_h = (float*)(smem + 73728);
  float* s_v = (float*)(smem + 75776);

  // B staging: round r covers rows r*128 + tid>>2; phys slot tid&3;
  // logical 16B-slot = ((tid&3) - ((tid>>3)&3)) & 3
  const unsigned short* bsrc0 = wab + (size_t)(tid >> 2) * 2048 +
      ((((tid & 3) - ((tid >> 3) & 3)) & 3) << 3);
  // A staging (reg->cvt->ds_write): row tid>>3, 4 f32 at (tid&7)*4
  const float* asrc = feat + (size_t)(m0 + (tid >> 3)) * 2048 + ((tid & 7) << 2);
  const int aw_off = ((tid >> 3) << 6) +
      ((((((tid >> 1) & 3) + ((tid >> 4) & 3)) & 3)) << 4) + ((tid & 1) << 3);

  // fragment read offsets: pslot is lane-uniform across frags
  const int psl = ((lk + (lrow >> 1)) & 3) << 4;
  const int a_roff = ((wm * 32 + lrow) << 6) + psl;
  const int b_roff = ((wn * 128 + lrow) << 6) + psl;

  f32x4 acc[2][8] = {};

  // ---- prologue: stage tile 0 into buf0
  s_h[tid] = hcomb[bb * 512 + tid];
  s_v[tid] = vw[tid];
  {
    char* bd = smem + (w << 10);
    GLOAD_LDS16(bsrc0,              bd);
    GLOAD_LDS16(bsrc0 + 128 * 2048, bd + 8192);
    GLOAD_LDS16(bsrc0 + 256 * 2048, bd + 16384);
    GLOAD_LDS16(bsrc0 + 384 * 2048, bd + 24576);
    float4 av = *(const float4*)(asrc);
    WAITV0; SCHEDB;
    ushort4 ap;
    ap.x = f2bf(av.x); ap.y = f2bf(av.y); ap.z = f2bf(av.z); ap.w = f2bf(av.w);
    *(ushort4*)(smem + 65536 + aw_off) = ap;
    WAITL0; SBAR;
  }

  #pragma unroll 2
  for (int t = 0; t < 64; ++t) {
    const int cur = t & 1, nxt = cur ^ 1;
    const int k1 = ((t + 1) & 63) << 5;
    // stage B(t+1) -> nxt (async, stays in flight under MFMA phase)
    const unsigned short* bs = bsrc0 + k1;
    char* bd = smem + nxt * 32768 + (w << 10);
    GLOAD_LDS16(bs,              bd);
    GLOAD_LDS16(bs + 128 * 2048, bd + 8192);
    GLOAD_LDS16(bs + 256 * 2048, bd + 16384);
    GLOAD_LDS16(bs + 384 * 2048, bd + 24576);
    // A(t+1) -> regs (compiler-managed vmcnt)
    float4 av = *(const float4*)(asrc + k1);

    // compute current tile
    const char* Ab = smem + 65536 + cur * 4096 + a_roff;
    const char* Bb = smem + cur * 32768 + b_roff;
    short8 a0 = *(const short8*)(Ab);
    short8 a1 = *(const short8*)(Ab + 1024);
    short8 b0 = *(const short8*)(Bb);
    short8 b1 = *(const short8*)(Bb + 1024);
    short8 b2 = *(const short8*)(Bb + 2048);
    short8 b3 = *(const short8*)(Bb + 3072);
    acc[0][0] = __builtin_amdgcn_mfma_f32_16x16x32_bf16(a0, b0, acc[0][0], 0, 0, 0);
    acc[1][0] = __builtin_amdgcn_mfma_f32_16x16x32_bf16(a1, b0, acc[1][0], 0, 0, 0);
    acc[0][1] = __builtin_amdgcn_mfma_f32_16x16x32_bf16(a0, b1, acc[0][1], 0, 0, 0);
    acc[1][1] = __builtin_amdgcn_mfma_f32_16x16x32_bf16(a1, b1, acc[1][1], 0, 0, 0);
    acc[0][2] = __builtin_amdgcn_mfma_f32_16x16x32_bf16(a0, b2, acc[0][2], 0, 0, 0);
    acc[1][2] = __builtin_amdgcn_mfma_f32_16x16x32_bf16(a1, b2, acc[1][2], 0, 0, 0);
    acc[0][3] = __builtin_amdgcn_mfma_f32_16x16x32_bf16(a0, b3, acc[0][3], 0, 0, 0);
    acc[1][3] = __builtin_amdgcn_mfma_f32_16x16x32_bf16(a1, b3, acc[1][3], 0, 0, 0);
    short8 b4 = *(const short8*)(Bb + 4096);
    short8 b5 = *(const short8*)(Bb + 5120);
    short8 b6 = *(const short8*)(Bb + 6144);
    short8 b7 = *(const short8*)(Bb + 7168);
    acc[0][4] = __builtin_amdgcn_mfma_f32_16x16x32_bf16(a0, b4, acc[0][4], 0, 0, 0);
    acc[1][4] = __builtin_amdgcn_mfma_f32_16x16x32_bf16(a1, b4, acc[1][4], 0, 0, 0);
    acc[0][5] = __builtin_amdgcn_mfma_f32_16x16x32_bf16(a0, b5, acc[0][5], 0, 0, 0);
    acc[1][5] = __builtin_amdgcn_mfma_f32_16x16x32_bf16(a1, b5, acc[1][5], 0, 0, 0);
    acc[0][6] = __builtin_amdgcn_mfma_f32_16x16x32_bf16(a0, b6, acc[0][6], 0, 0, 0);
    acc[1][6] = __builtin_amdgcn_mfma_f32_16x16x32_bf16(a1, b6, acc[1][6], 0, 0, 0);
    acc[0][7] = __builtin_amdgcn_mfma_f32_16x16x32_bf16(a0, b7, acc[0][7], 0, 0, 0);
    acc[1][7] = __builtin_amdgcn_mfma_f32_16x16x32_bf16(a1, b7, acc[1][7], 0, 0, 0);

    // write A(t+1) into nxt (compiler inserts its own vmcnt for av)
    ushort4 ap;
    ap.x = f2bf(av.x); ap.y = f2bf(av.y); ap.z = f2bf(av.z); ap.w = f2bf(av.w);
    *(ushort4*)(smem + 65536 + nxt * 4096 + aw_off) = ap;

    WAITL0;   // A ds_write visible to all waves after barrier
    WAITV0;   // B(t+1) gload_lds complete (latency hidden under MFMA phase)
    SBAR;
  }

  // ---- epilogue: tanh, dot with v, reduce over N=512
  float (*e_red)[4] = (float(*)[4])(smem + 77824);
  const float vbv = vb[0];
  #pragma unroll
  for (int mi = 0; mi < 2; ++mi) {
    #pragma unroll
    for (int j = 0; j < 4; ++j) {
      float s = 0.f;
      #pragma unroll
      for (int ni = 0; ni < 8; ++ni) {
        int col = wn * 128 + ni * 16 + lrow;
        float x = acc[mi][ni][j] + s_h[col];
        s += tanhf(x) * s_v[col];
      }
      s += __shfl_xor(s, 1); s += __shfl_xor(s, 2);
      s += __shfl_xor(s, 4); s += __shfl_xor(s, 8);
      if (lrow == 0) e_red[wm * 32 + mi * 16 + (lane >> 4) * 4 + j][wn] = s;
    }
  }
  __syncthreads();
  if (tid < 64) {
    float s = e_red[tid][0] + e_red[tid][1] + e_red[tid][2] + e_red[tid][3];
    energy[m0 + tid] = (s + vbv) * 0.04419417382415922f;  // 1/sqrt(512)
  }
}

// ---------------- kernel 4: softmax over T per batch ----------------
__global__ __launch_bounds__(256) void k_softmax(const float* __restrict__ energy,
                                                 float* __restrict__ alpha) {
  const int b = blockIdx.x, tid = threadIdx.x;
  const float* e = energy + b * T_;
  float4 v0 = ((const float4*)e)[tid * 2];
  float4 v1 = ((const float4*)e)[tid * 2 + 1];
  float m = fmaxf(fmaxf(fmaxf(v0.x, v0.y), fmaxf(v0.z, v0.w)),
                  fmaxf(fmaxf(v1.x, v1.y), fmaxf(v1.z, v1.w)));
  #pragma unroll
  for (int off = 32; off; off >>= 1) m = fmaxf(m, __shfl_xor(m, off));
  __shared__ float rmax[4], rsum[4];
  const int lane = tid & 63, wv = tid >> 6;
  if (!lane) rmax[wv] = m;
  __syncthreads();
  m = fmaxf(fmaxf(rmax[0], rmax[1]), fmaxf(rmax[2], rmax[3]));
  float x0 = expf(v0.x - m), x1 = expf(v0.y - m), x2 = expf(v0.z - m), x3 = expf(v0.w - m);
  float x4 = expf(v1.x - m), x5 = expf(v1.y - m), x6 = expf(v1.z - m), x7 = expf(v1.w - m);
  float s = ((x0 + x1) + (x2 + x3)) + ((x4 + x5) + (x6 + x7));
  #pragma unroll
  for (int off = 32; off; off >>= 1) s += __shfl_xor(s, off);
  if (!lane) rsum[wv] = s;
  __syncthreads();
  s = (rsum[0] + rsum[1]) + (rsum[2] + rsum[3]);
  float inv = 1.f / s;
  float4 o0 = {x0 * inv, x1 * inv, x2 * inv, x3 * inv};
  float4 o1 = {x4 * inv, x5 * inv, x6 * inv, x7 * inv};
  float* ao = alpha + b * T_;
  ((float4*)ao)[tid * 2] = o0;
  ((float4*)ao)[tid * 2 + 1] = o1;
}

// ---------------- kernel 5: context partials over t-chunks ----------------
__global__ __launch_bounds__(256) void k_ctx_partial(const float* __restrict__ feat,
                                                     const float* __restrict__ alpha,
                                                     float* __restrict__ part) {
  const int b = blockIdx.x, fh = blockIdx.y, tc = blockIdx.z;
  const int tid = threadIdx.x;
  __shared__ float sa[128];
  if (tid < 128) sa[tid] = alpha[b * T_ + tc * 128 + tid];
  __syncthreads();
  const int f = fh * 1024 + tid * 4;
  const float* fp = feat + ((size_t)(b * T_ + tc * 128)) * F_ + f;
  float4 s = {0.f, 0.f, 0.f, 0.f};
  #pragma unroll 4
  for (int t = 0; t < 128; ++t) {
    float a = sa[t];
    float4 v = *(const float4*)(fp + (size_t)t * F_);
    s.x += a * v.x; s.y += a * v.y; s.z += a * v.z; s.w += a * v.w;
  }
  *(float4*)(part + ((size_t)(b * 16 + tc)) * F_ + f) = s;
}

// ---------------- kernel 6: reduce partials ----------------
__global__ __launch_bounds__(256) void k_ctx_reduce(const float* __restrict__ part,
                                                    float* __restrict__ ctx) {
  const int i4 = blockIdx.x * 256 + threadIdx.x;  // float4 index, 16384 total
  const int b = i4 >> 9, f4 = i4 & 511;
  const float4* p = (const float4*)part;
  float4 s = {0.f, 0.f, 0.f, 0.f};
  #pragma unroll
  for (int tc = 0; tc < 16; ++tc) {
    float4 v = p[((b * 16 + tc) << 9) + f4];
    s.x += v.x; s.y += v.y; s.z += v.z; s.w += v.w;
  }
  ((float4*)ctx)[i4] = s;
}

extern "C" void kernel_launch(void* const* d_in, const int* in_sizes, int n_in,
                              void* d_out, int out_size, void* d_ws, size_t ws_size,
                              hipStream_t stream) {
  const float* feat   = (const float*)d_in[0];
  const float* hidden = (const float*)d_in[1];
  const float* Wh     = (const float*)d_in[2];
  const float* bh     = (const float*)d_in[3];
  const float* Wa     = (const float*)d_in[4];
  const float* ba     = (const float*)d_in[5];
  const float* vw     = (const float*)d_in[6];
  const float* vb     = (const float*)d_in[7];

  float* ctx   = (float*)d_out;            // [32][2048]
  float* alpha = (float*)d_out + B_ * T_;  // [32][2048]

  char* ws = (char*)d_ws;
  unsigned short* wab = (unsigned short*)ws;               // 2 MB bf16 W_a
  float* hcomb  = (float*)(ws + 2097152);                  // 64 KB
  float* energy = (float*)(ws + 2097152 + 65536);          // 256 KB
  float* part   = (float*)(ws + 2097152 + 65536 + 262144); // 4 MB

  k_convert_wa<<<dim3(1024), dim3(256), 0, stream>>>(Wa, wab);
  k_hproj<<<dim3(4096), dim3(256), 0, stream>>>(hidden, Wh, bh, ba, hcomb);
  k_energy<<<dim3(1024), dim3(512), 0, stream>>>(feat, wab, hcomb, vw, vb, energy);
  k_softmax<<<dim3(32), dim3(256), 0, stream>>>(energy, alpha);
  k_ctx_partial<<<dim3(32, 2, 16), dim3(256), 0, stream>>>(feat, alpha, part);
  k_ctx_reduce<<<dim3(64), dim3(256), 0, stream>>>(part, ctx);
}

// Round 3
// 343.901 us; speedup vs baseline: 1.0310x; 1.0310x over previous
//
#include <hip/hip_runtime.h>
#include <hip/hip_bf16.h>
#include <math.h>

#define B_ 32
#define T_ 2048
#define F_ 2048
#define H_ 1024
#define A_ 512

typedef __attribute__((ext_vector_type(8))) short short8;
typedef __attribute__((ext_vector_type(4))) float f32x4;

__device__ __forceinline__ unsigned short f2bf(float x) {
  union { float f; unsigned int u; } v; v.f = x;
  unsigned int r = v.u + 0x7FFFu + ((v.u >> 16) & 1u);
  return (unsigned short)(r >> 16);
}

#define GLOAD_LDS16(gp, lp) __builtin_amdgcn_global_load_lds( \
    (const __attribute__((address_space(1))) void*)(gp), \
    (__attribute__((address_space(3))) void*)(lp), 16, 0, 0)

#define SBAR   asm volatile("s_barrier" ::: "memory")
#define SCHEDB __builtin_amdgcn_sched_barrier(0)
#define WAIT_V1_L0 asm volatile("s_waitcnt vmcnt(1) lgkmcnt(0)" ::: "memory")

// ---------------- kernel 1: W_a f32 -> bf16 ----------------
__global__ __launch_bounds__(256) void k_convert_wa(const float* __restrict__ wa,
                                                    unsigned short* __restrict__ out) {
  int i = (blockIdx.x * 256 + threadIdx.x) * 4;
  float4 v = *(const float4*)(wa + i);
  ushort4 o;
  o.x = f2bf(v.x); o.y = f2bf(v.y); o.z = f2bf(v.z); o.w = f2bf(v.w);
  *(ushort4*)(out + i) = o;
}

// ---------------- kernel 2: hcomb[b][a] = hidden[b]·W_h[a] + b_h[a] + b_a[a] ----------------
__global__ __launch_bounds__(256) void k_hproj(const float* __restrict__ hidden,
                                               const float* __restrict__ Wh,
                                               const float* __restrict__ bh,
                                               const float* __restrict__ ba,
                                               float* __restrict__ hcomb) {
  int gw = (blockIdx.x * 256 + threadIdx.x) >> 6;   // wave id 0..16383
  int lane = threadIdx.x & 63;
  int b = gw >> 9, a = gw & 511;
  const float* wr = Wh + a * H_;
  const float* hr = hidden + b * H_;
  float acc = 0.f;
  #pragma unroll
  for (int k = 0; k < H_; k += 256) {
    float4 wv = *(const float4*)(wr + k + lane * 4);
    float4 hv = *(const float4*)(hr + k + lane * 4);
    acc += wv.x * hv.x + wv.y * hv.y + wv.z * hv.z + wv.w * hv.w;
  }
  #pragma unroll
  for (int off = 32; off; off >>= 1) acc += __shfl_xor(acc, off);
  if (lane == 0) hcomb[gw] = acc + bh[a] + ba[a];
}

// ---------------- kernel 3: fused energy GEMM ----------------
// energy[m] = (sum_a tanh(hcomb[b][a] + feat[m]·W_a[a]) * v_w[a] + v_b) / sqrt(512)
// M=65536, K=2048, N=512 full per block. BM=64, BK=32, double-buffered LDS.
// Counted-vmcnt schedule (T4): per iter issue B(t+1) gload_lds first, A(t+2)
// reg-load last; end-of-iter s_waitcnt vmcnt(1) retains ONLY A(t+2) in flight.
// Never drains vmcnt to 0 in the loop.
__global__ __launch_bounds__(512, 4) void k_energy(
    const float* __restrict__ feat, const unsigned short* __restrict__ wab,
    const float* __restrict__ hcomb, const float* __restrict__ vw,
    const float* __restrict__ vb, float* __restrict__ energy) {
  // layout: Bs 2x32768 | As 2x4096 @65536 | s_h @73728 | s_v @75776 | e_red @77824
  __shared__ __align__(16) char smem[78848];

  const int tid = threadIdx.x;
  const int lane = tid & 63;
  const int w = tid >> 6;
  const int wm = w >> 2, wn = w & 3;
  const int lrow = lane & 15, lk = lane >> 4;
  const int m0 = blockIdx.x * 64;
  const int bb = m0 >> 11;

  float* s_h = (float*)(smem + 73728);
  float* s_v = (float*)(smem + 75776);

  // B staging: round r covers rows r*128 + tid>>2; phys slot tid&3;
  // logical 16B-slot = ((tid&3) - ((tid>>3)&3)) & 3
  const unsigned short* bsrc0 = wab + (size_t)(tid >> 2) * 2048 +
      ((((tid & 3) - ((tid >> 3) & 3)) & 3) << 3);
  // A staging (reg->cvt->ds_write): row tid>>3, 4 f32 at (tid&7)*4
  const float* asrc = feat + (size_t)(m0 + (tid >> 3)) * 2048 + ((tid & 7) << 2);
  const int aw_off = ((tid >> 3) << 6) +
      ((((((tid >> 1) & 3) + ((tid >> 4) & 3)) & 3)) << 4) + ((tid & 1) << 3);

  // fragment read offsets: pslot is lane-uniform across frags
  const int psl = ((lk + (lrow >> 1)) & 3) << 4;
  const int a_roff = ((wm * 32 + lrow) << 6) + psl;
  const int b_roff = ((wn * 128 + lrow) << 6) + psl;

  f32x4 acc[2][8] = {};
  float4 avA, avB;

  // ---- prologue: stage tile 0 into buf0; leave A(1) in flight
  s_h[tid] = hcomb[bb * 512 + tid];
  s_v[tid] = vw[tid];
  {
    avA = *(const float4*)(asrc);           // A(0)
    char* bd = smem + (w << 10);
    GLOAD_LDS16(bsrc0,              bd);
    GLOAD_LDS16(bsrc0 + 128 * 2048, bd + 8192);
    GLOAD_LDS16(bsrc0 + 256 * 2048, bd + 16384);
    GLOAD_LDS16(bsrc0 + 384 * 2048, bd + 24576);
    SCHEDB;
    avB = *(const float4*)(asrc + 32);      // A(1) — newest, stays in flight
    SCHEDB;
    ushort4 ap;
    ap.x = f2bf(avA.x); ap.y = f2bf(avA.y); ap.z = f2bf(avA.z); ap.w = f2bf(avA.w);
    *(ushort4*)(smem + 65536 + aw_off) = ap;
    SCHEDB;
    WAIT_V1_L0;   // drain sh/sv/A(0)/B(0)x4; retain A(1)
    SBAR;
  }

#define ENERGY_BODY(CUR, NXT, CONS, SLOT, K1, K2) do {                        \
    const unsigned short* bs_ = bsrc0 + (K1);                                 \
    char* bd_ = smem + (NXT) * 32768 + (w << 10);                             \
    GLOAD_LDS16(bs_,              bd_);                                       \
    GLOAD_LDS16(bs_ + 128 * 2048, bd_ + 8192);                                \
    GLOAD_LDS16(bs_ + 256 * 2048, bd_ + 16384);                               \
    GLOAD_LDS16(bs_ + 384 * 2048, bd_ + 24576);                               \
    SCHEDB;                                                                   \
    {                                                                         \
      const char* Ab = smem + 65536 + (CUR) * 4096 + a_roff;                  \
      const char* Bb = smem + (CUR) * 32768 + b_roff;                         \
      short8 a0 = *(const short8*)(Ab);                                       \
      short8 a1 = *(const short8*)(Ab + 1024);                                \
      short8 b0 = *(const short8*)(Bb);                                       \
      short8 b1 = *(const short8*)(Bb + 1024);                                \
      short8 b2 = *(const short8*)(Bb + 2048);                                \
      short8 b3 = *(const short8*)(Bb + 3072);                                \
      acc[0][0] = __builtin_amdgcn_mfma_f32_16x16x32_bf16(a0, b0, acc[0][0], 0, 0, 0); \
      acc[1][0] = __builtin_amdgcn_mfma_f32_16x16x32_bf16(a1, b0, acc[1][0], 0, 0, 0); \
      acc[0][1] = __builtin_amdgcn_mfma_f32_16x16x32_bf16(a0, b1, acc[0][1], 0, 0, 0); \
      acc[1][1] = __builtin_amdgcn_mfma_f32_16x16x32_bf16(a1, b1, acc[1][1], 0, 0, 0); \
      acc[0][2] = __builtin_amdgcn_mfma_f32_16x16x32_bf16(a0, b2, acc[0][2], 0, 0, 0); \
      acc[1][2] = __builtin_amdgcn_mfma_f32_16x16x32_bf16(a1, b2, acc[1][2], 0, 0, 0); \
      acc[0][3] = __builtin_amdgcn_mfma_f32_16x16x32_bf16(a0, b3, acc[0][3], 0, 0, 0); \
      acc[1][3] = __builtin_amdgcn_mfma_f32_16x16x32_bf16(a1, b3, acc[1][3], 0, 0, 0); \
      short8 b4 = *(const short8*)(Bb + 4096);                                \
      short8 b5 = *(const short8*)(Bb + 5120);                                \
      short8 b6 = *(const short8*)(Bb + 6144);                                \
      short8 b7 = *(const short8*)(Bb + 7168);                                \
      acc[0][4] = __builtin_amdgcn_mfma_f32_16x16x32_bf16(a0, b4, acc[0][4], 0, 0, 0); \
      acc[1][4] = __builtin_amdgcn_mfma_f32_16x16x32_bf16(a1, b4, acc[1][4], 0, 0, 0); \
      acc[0][5] = __builtin_amdgcn_mfma_f32_16x16x32_bf16(a0, b5, acc[0][5], 0, 0, 0); \
      acc[1][5] = __builtin_amdgcn_mfma_f32_16x16x32_bf16(a1, b5, acc[1][5], 0, 0, 0); \
      acc[0][6] = __builtin_amdgcn_mfma_f32_16x16x32_bf16(a0, b6, acc[0][6], 0, 0, 0); \
      acc[1][6] = __builtin_amdgcn_mfma_f32_16x16x32_bf16(a1, b6, acc[1][6], 0, 0, 0); \
      acc[0][7] = __builtin_amdgcn_mfma_f32_16x16x32_bf16(a0, b7, acc[0][7], 0, 0, 0); \
      acc[1][7] = __builtin_amdgcn_mfma_f32_16x16x32_bf16(a1, b7, acc[1][7], 0, 0, 0); \
    }                                                                         \
    {                                                                         \
      ushort4 ap_;   /* compiler inserts precise vmcnt(4) for CONS here */    \
      ap_.x = f2bf((CONS).x); ap_.y = f2bf((CONS).y);                         \
      ap_.z = f2bf((CONS).z); ap_.w = f2bf((CONS).w);                         \
      *(ushort4*)(smem + 65536 + (NXT) * 4096 + aw_off) = ap_;                \
    }                                                                         \
    SCHEDB;                                                                   \
    (SLOT) = *(const float4*)(asrc + (K2));  /* A(t+2), newest */             \
    SCHEDB;                                                                   \
    WAIT_V1_L0;  /* B(t+1) done + A ds_write done; A(t+2) stays in flight */  \
    SBAR;                                                                     \
  } while (0)

  #pragma unroll 1
  for (int t = 0; t < 64; t += 2) {
    ENERGY_BODY(0, 1, avB, avA, (((t + 1) & 63) << 5), (((t + 2) & 63) << 5));
    ENERGY_BODY(1, 0, avA, avB, (((t + 2) & 63) << 5), (((t + 3) & 63) << 5));
  }
#undef ENERGY_BODY

  // ---- epilogue: tanh, dot with v, reduce over N=512
  float (*e_red)[4] = (float(*)[4])(smem + 77824);
  const float vbv = vb[0];
  #pragma unroll
  for (int mi = 0; mi < 2; ++mi) {
    #pragma unroll
    for (int j = 0; j < 4; ++j) {
      float s = 0.f;
      #pragma unroll
      for (int ni = 0; ni < 8; ++ni) {
        int col = wn * 128 + ni * 16 + lrow;
        float x = acc[mi][ni][j] + s_h[col];
        s += tanhf(x) * s_v[col];
      }
      s += __shfl_xor(s, 1); s += __shfl_xor(s, 2);
      s += __shfl_xor(s, 4); s += __shfl_xor(s, 8);
      if (lrow == 0) e_red[wm * 32 + mi * 16 + (lane >> 4) * 4 + j][wn] = s;
    }
  }
  __syncthreads();
  if (tid < 64) {
    float s = e_red[tid][0] + e_red[tid][1] + e_red[tid][2] + e_red[tid][3];
    energy[m0 + tid] = (s + vbv) * 0.04419417382415922f;  // 1/sqrt(512)
  }
}

// ---------------- kernel 4: softmax over T per batch ----------------
__global__ __launch_bounds__(256) void k_softmax(const float* __restrict__ energy,
                                                 float* __restrict__ alpha) {
  const int b = blockIdx.x, tid = threadIdx.x;
  const float* e = energy + b * T_;
  float4 v0 = ((const float4*)e)[tid * 2];
  float4 v1 = ((const float4*)e)[tid * 2 + 1];
  float m = fmaxf(fmaxf(fmaxf(v0.x, v0.y), fmaxf(v0.z, v0.w)),
                  fmaxf(fmaxf(v1.x, v1.y), fmaxf(v1.z, v1.w)));
  #pragma unroll
  for (int off = 32; off; off >>= 1) m = fmaxf(m, __shfl_xor(m, off));
  __shared__ float rmax[4], rsum[4];
  const int lane = tid & 63, wv = tid >> 6;
  if (!lane) rmax[wv] = m;
  __syncthreads();
  m = fmaxf(fmaxf(rmax[0], rmax[1]), fmaxf(rmax[2], rmax[3]));
  float x0 = expf(v0.x - m), x1 = expf(v0.y - m), x2 = expf(v0.z - m), x3 = expf(v0.w - m);
  float x4 = expf(v1.x - m), x5 = expf(v1.y - m), x6 = expf(v1.z - m), x7 = expf(v1.w - m);
  float s = ((x0 + x1) + (x2 + x3)) + ((x4 + x5) + (x6 + x7));
  #pragma unroll
  for (int off = 32; off; off >>= 1) s += __shfl_xor(s, off);
  if (!lane) rsum[wv] = s;
  __syncthreads();
  s = (rsum[0] + rsum[1]) + (rsum[2] + rsum[3]);
  float inv = 1.f / s;
  float4 o0 = {x0 * inv, x1 * inv, x2 * inv, x3 * inv};
  float4 o1 = {x4 * inv, x5 * inv, x6 * inv, x7 * inv};
  float* ao = alpha + b * T_;
  ((float4*)ao)[tid * 2] = o0;
  ((float4*)ao)[tid * 2 + 1] = o1;
}

// ---------------- kernel 5: context partials over t-chunks ----------------
__global__ __launch_bounds__(256) void k_ctx_partial(const float* __restrict__ feat,
                                                     const float* __restrict__ alpha,
                                                     float* __restrict__ part) {
  const int b = blockIdx.x, fh = blockIdx.y, tc = blockIdx.z;
  const int tid = threadIdx.x;
  __shared__ float sa[128];
  if (tid < 128) sa[tid] = alpha[b * T_ + tc * 128 + tid];
  __syncthreads();
  const int f = fh * 1024 + tid * 4;
  const float* fp = feat + ((size_t)(b * T_ + tc * 128)) * F_ + f;
  float4 s = {0.f, 0.f, 0.f, 0.f};
  #pragma unroll 4
  for (int t = 0; t < 128; ++t) {
    float a = sa[t];
    float4 v = *(const float4*)(fp + (size_t)t * F_);
    s.x += a * v.x; s.y += a * v.y; s.z += a * v.z; s.w += a * v.w;
  }
  *(float4*)(part + ((size_t)(b * 16 + tc)) * F_ + f) = s;
}

// ---------------- kernel 6: reduce partials ----------------
__global__ __launch_bounds__(256) void k_ctx_reduce(const float* __restrict__ part,
                                                    float* __restrict__ ctx) {
  const int i4 = blockIdx.x * 256 + threadIdx.x;  // float4 index, 16384 total
  const int b = i4 >> 9, f4 = i4 & 511;
  const float4* p = (const float4*)part;
  float4 s = {0.f, 0.f, 0.f, 0.f};
  #pragma unroll
  for (int tc = 0; tc < 16; ++tc) {
    float4 v = p[((b * 16 + tc) << 9) + f4];
    s.x += v.x; s.y += v.y; s.z += v.z; s.w += v.w;
  }
  ((float4*)ctx)[i4] = s;
}

extern "C" void kernel_launch(void* const* d_in, const int* in_sizes, int n_in,
                              void* d_out, int out_size, void* d_ws, size_t ws_size,
                              hipStream_t stream) {
  const float* feat   = (const float*)d_in[0];
  const float* hidden = (const float*)d_in[1];
  const float* Wh     = (const float*)d_in[2];
  const float* bh     = (const float*)d_in[3];
  const float* Wa     = (const float*)d_in[4];
  const float* ba     = (const float*)d_in[5];
  const float* vw     = (const float*)d_in[6];
  const float* vb     = (const float*)d_in[7];

  float* ctx   = (float*)d_out;            // [32][2048]
  float* alpha = (float*)d_out + B_ * T_;  // [32][2048]

  char* ws = (char*)d_ws;
  unsigned short* wab = (unsigned short*)ws;               // 2 MB bf16 W_a
  float* hcomb  = (float*)(ws + 2097152);                  // 64 KB
  float* energy = (float*)(ws + 2097152 + 65536);          // 256 KB
  float* part   = (float*)(ws + 2097152 + 65536 + 262144); // 4 MB

  k_convert_wa<<<dim3(1024), dim3(256), 0, stream>>>(Wa, wab);
  k_hproj<<<dim3(4096), dim3(256), 0, stream>>>(hidden, Wh, bh, ba, hcomb);
  k_energy<<<dim3(1024), dim3(512), 0, stream>>>(feat, wab, hcomb, vw, vb, energy);
  k_softmax<<<dim3(32), dim3(256), 0, stream>>>(energy, alpha);
  k_ctx_partial<<<dim3(32, 2, 16), dim3(256), 0, stream>>>(feat, alpha, part);
  k_ctx_reduce<<<dim3(64), dim3(256), 0, stream>>>(part, ctx);
}

// Round 4
// 299.913 us; speedup vs baseline: 1.1823x; 1.1467x over previous
//
#include <hip/hip_runtime.h>
#include <hip/hip_bf16.h>
#include <math.h>

#define B_ 32
#define T_ 2048
#define F_ 2048
#define H_ 1024
#define A_ 512

typedef __attribute__((ext_vector_type(8))) short short8;
typedef __attribute__((ext_vector_type(4))) float f32x4;

__device__ __forceinline__ unsigned short f2bf(float x) {
  union { float f; unsigned int u; } v; v.f = x;
  unsigned int r = v.u + 0x7FFFu + ((v.u >> 16) & 1u);
  return (unsigned short)(r >> 16);
}

#define GLOAD_LDS16(gp, lp) __builtin_amdgcn_global_load_lds( \
    (const __attribute__((address_space(1))) void*)(gp), \
    (__attribute__((address_space(3))) void*)(lp), 16, 0, 0)

#define SBAR   asm volatile("s_barrier" ::: "memory")
#define SCHEDB __builtin_amdgcn_sched_barrier(0)

// ---------------- kernel 1: W_a f32 -> bf16 ----------------
__global__ __launch_bounds__(256) void k_convert_wa(const float* __restrict__ wa,
                                                    unsigned short* __restrict__ out) {
  int i = (blockIdx.x * 256 + threadIdx.x) * 4;
  float4 v = *(const float4*)(wa + i);
  ushort4 o;
  o.x = f2bf(v.x); o.y = f2bf(v.y); o.z = f2bf(v.z); o.w = f2bf(v.w);
  *(ushort4*)(out + i) = o;
}

// ---------------- kernel 2: hcomb[b][a] = hidden[b]·W_h[a] + b_h[a] + b_a[a] ----------------
__global__ __launch_bounds__(256) void k_hproj(const float* __restrict__ hidden,
                                               const float* __restrict__ Wh,
                                               const float* __restrict__ bh,
                                               const float* __restrict__ ba,
                                               float* __restrict__ hcomb) {
  int gw = (blockIdx.x * 256 + threadIdx.x) >> 6;   // wave id 0..16383
  int lane = threadIdx.x & 63;
  int b = gw >> 9, a = gw & 511;
  const float* wr = Wh + a * H_;
  const float* hr = hidden + b * H_;
  float acc = 0.f;
  #pragma unroll
  for (int k = 0; k < H_; k += 256) {
    float4 wv = *(const float4*)(wr + k + lane * 4);
    float4 hv = *(const float4*)(hr + k + lane * 4);
    acc += wv.x * hv.x + wv.y * hv.y + wv.z * hv.z + wv.w * hv.w;
  }
  #pragma unroll
  for (int off = 32; off; off >>= 1) acc += __shfl_xor(acc, off);
  if (lane == 0) hcomb[gw] = acc + bh[a] + ba[a];
}

// ---------------- kernel 3: fused energy GEMM ----------------
// energy[m] = (sum_a tanh(hcomb[b][a] + feat[m]·W_a[a]) * v_w[a] + v_b) / sqrt(512)
// M=65536, K=2048, N=512 full per block. BM=64, BK=64, 32 iters, 2 barriers/iter
// (round-1 structure). Change vs round-1: A(t+1) f32 loads issued at TOP of
// compute(t) (HBM latency hides under MFMA phase); raw SBAR between compute and
// stage (no drain); __syncthreads at iter end drains ONLY B(t+1)+A ds_write.
// As double-buffered (2x8KB); Bs single (64KB); total LDS 80KB -> 2 blocks/CU.
__global__ __launch_bounds__(512, 4) void k_energy(
    const float* __restrict__ feat, const unsigned short* __restrict__ wab,
    const float* __restrict__ hcomb, const float* __restrict__ vw,
    const float* __restrict__ vb, float* __restrict__ energy) {
  // layout: Bs [0,65536) | As0 [65536,73728) | As1 [73728,81920)
  // e_red reuses [65536,66560) after the K-loop (As dead by then).
  __shared__ __align__(16) char smem[81920];

  const int tid = threadIdx.x;
  const int lane = tid & 63;
  const int w = tid >> 6;
  const int wm = w >> 2, wn = w & 3;
  const int lrow = lane & 15;
  const int m0 = blockIdx.x * 64;
  const int bb = m0 >> 11;

  // ---- B staging (identical geometry to round-1, BK=64):
  // round r covers rows r*64 + (tid>>3); phys 16B-slot tid&7;
  // logical slot = phys ^ (row&7)  (XOR involution per 128B row)
  const int brow = tid >> 3;
  const unsigned short* const bsrc0 = wab + (size_t)brow * 2048 +
      (((((tid & 7) << 4) ^ ((brow & 7) << 4)) >> 1));
  char* const ldsb = smem + w * 1024;

  // ---- A staging: row tid>>3 (64 rows), slot tid&7 (8 k-elems of 16B)
  const int arow = tid >> 3;
  const float* const asrc = feat + (size_t)(m0 + arow) * F_ + ((tid & 7) << 3);
  const int aw_byte = (arow << 7) + ((((tid & 7) << 4)) ^ ((arow & 7) << 4));

  // ---- fragment read offsets (bytes); row&7 == lane&7 for all frag rows
  const int xbase = ((lane >> 4) << 4) ^ ((lane & 7) << 4);
  const int a_row_byte = (wm * 32 + lrow) << 7;
  const int b_row_byte = (wn * 128 + lrow) << 7;

  f32x4 acc[2][8] = {};

  // ---- prologue: A(0) issue first, then B(0); cvt waits vmcnt(8) (retains B)
  {
    float4 av0 = *(const float4*)(asrc);
    float4 av1 = *(const float4*)(asrc + 4);
    #pragma unroll
    for (int r = 0; r < 8; ++r)
      GLOAD_LDS16(bsrc0 + r * (64 * 2048), ldsb + r * 8192);
    short8 apk;
    apk[0] = (short)f2bf(av0.x); apk[1] = (short)f2bf(av0.y);
    apk[2] = (short)f2bf(av0.z); apk[3] = (short)f2bf(av0.w);
    apk[4] = (short)f2bf(av1.x); apk[5] = (short)f2bf(av1.y);
    apk[6] = (short)f2bf(av1.z); apk[7] = (short)f2bf(av1.w);
    *(short8*)(smem + 65536 + aw_byte) = apk;
    __syncthreads();   // drains B(0) gloads + A(0) ds_write
  }

#define COMPUTE_TILE(CURBUF) do {                                             \
    const char* As_ = smem + 65536 + (CURBUF) * 8192;                         \
    _Pragma("unroll")                                                         \
    for (int kk = 0; kk < 2; ++kk) {                                          \
      const int xo = xbase ^ (kk << 6);                                       \
      const char* Ab = As_ + a_row_byte + xo;                                 \
      const char* Bb = smem + b_row_byte + xo;                                \
      short8 a0 = *(const short8*)(Ab);                                       \
      short8 a1 = *(const short8*)(Ab + 2048);                                \
      short8 b0 = *(const short8*)(Bb);                                       \
      short8 b1 = *(const short8*)(Bb + 2048);                                \
      short8 b2 = *(const short8*)(Bb + 4096);                                \
      short8 b3 = *(const short8*)(Bb + 6144);                                \
      acc[0][0] = __builtin_amdgcn_mfma_f32_16x16x32_bf16(a0, b0, acc[0][0], 0, 0, 0); \
      acc[1][0] = __builtin_amdgcn_mfma_f32_16x16x32_bf16(a1, b0, acc[1][0], 0, 0, 0); \
      acc[0][1] = __builtin_amdgcn_mfma_f32_16x16x32_bf16(a0, b1, acc[0][1], 0, 0, 0); \
      acc[1][1] = __builtin_amdgcn_mfma_f32_16x16x32_bf16(a1, b1, acc[1][1], 0, 0, 0); \
      acc[0][2] = __builtin_amdgcn_mfma_f32_16x16x32_bf16(a0, b2, acc[0][2], 0, 0, 0); \
      acc[1][2] = __builtin_amdgcn_mfma_f32_16x16x32_bf16(a1, b2, acc[1][2], 0, 0, 0); \
      acc[0][3] = __builtin_amdgcn_mfma_f32_16x16x32_bf16(a0, b3, acc[0][3], 0, 0, 0); \
      acc[1][3] = __builtin_amdgcn_mfma_f32_16x16x32_bf16(a1, b3, acc[1][3], 0, 0, 0); \
      short8 b4 = *(const short8*)(Bb + 8192);                                \
      short8 b5 = *(const short8*)(Bb + 10240);                               \
      short8 b6 = *(const short8*)(Bb + 12288);                               \
      short8 b7 = *(const short8*)(Bb + 14336);                               \
      acc[0][4] = __builtin_amdgcn_mfma_f32_16x16x32_bf16(a0, b4, acc[0][4], 0, 0, 0); \
      acc[1][4] = __builtin_amdgcn_mfma_f32_16x16x32_bf16(a1, b4, acc[1][4], 0, 0, 0); \
      acc[0][5] = __builtin_amdgcn_mfma_f32_16x16x32_bf16(a0, b5, acc[0][5], 0, 0, 0); \
      acc[1][5] = __builtin_amdgcn_mfma_f32_16x16x32_bf16(a1, b5, acc[1][5], 0, 0, 0); \
      acc[0][6] = __builtin_amdgcn_mfma_f32_16x16x32_bf16(a0, b6, acc[0][6], 0, 0, 0); \
      acc[1][6] = __builtin_amdgcn_mfma_f32_16x16x32_bf16(a1, b6, acc[1][6], 0, 0, 0); \
      acc[0][7] = __builtin_amdgcn_mfma_f32_16x16x32_bf16(a0, b7, acc[0][7], 0, 0, 0); \
      acc[1][7] = __builtin_amdgcn_mfma_f32_16x16x32_bf16(a1, b7, acc[1][7], 0, 0, 0); \
    }                                                                         \
  } while (0)

  #pragma unroll 1
  for (int t = 0; t < 31; ++t) {
    const int cur = t & 1, nxt = cur ^ 1;
    const int k1 = (t + 1) << 6;
    // issue A(t+1) -> regs at compute start (latency hides under MFMAs)
    float4 av0 = *(const float4*)(asrc + k1);
    float4 av1 = *(const float4*)(asrc + k1 + 4);
    SCHEDB;
    COMPUTE_TILE(cur);
    SBAR;   // raw: all ds_reads already consumed by MFMAs; no drain
    // stage phase: B(t+1) into Bs (post-barrier overwrite safe)
    const unsigned short* bs = bsrc0 + k1;
    #pragma unroll
    for (int r = 0; r < 8; ++r)
      GLOAD_LDS16(bs + r * (64 * 2048), ldsb + r * 8192);
    // cvt A(t+1): compiler inserts vmcnt(8) (retains the 8 B gloads)
    short8 apk;
    apk[0] = (short)f2bf(av0.x); apk[1] = (short)f2bf(av0.y);
    apk[2] = (short)f2bf(av0.z); apk[3] = (short)f2bf(av0.w);
    apk[4] = (short)f2bf(av1.x); apk[5] = (short)f2bf(av1.y);
    apk[6] = (short)f2bf(av1.z); apk[7] = (short)f2bf(av1.w);
    *(short8*)(smem + 65536 + nxt * 8192 + aw_byte) = apk;
    __syncthreads();   // drains ONLY B(t+1) gloads + A ds_write (A(t+2) not yet issued)
  }
  COMPUTE_TILE(1);   // t=31, cur=1
#undef COMPUTE_TILE

  // ---- epilogue: tanh, dot with v, reduce over N=512
  // h/v read straight from L2 (hcomb 64KB + vw 2KB resident); 8 cols per lane.
  float hv[8], vv[8];
  #pragma unroll
  for (int ni = 0; ni < 8; ++ni) {
    int col = wn * 128 + ni * 16 + lrow;
    hv[ni] = hcomb[bb * 512 + col];
    vv[ni] = vw[col];
  }
  float (*e_red)[4] = (float(*)[4])(smem + 65536);
  __syncthreads();   // As reads done; safe to reuse As0 space for e_red
  const float vbv = vb[0];
  #pragma unroll
  for (int mi = 0; mi < 2; ++mi) {
    #pragma unroll
    for (int j = 0; j < 4; ++j) {
      float s = 0.f;
      #pragma unroll
      for (int ni = 0; ni < 8; ++ni) {
        float x = acc[mi][ni][j] + hv[ni];
        s += tanhf(x) * vv[ni];
      }
      s += __shfl_xor(s, 1); s += __shfl_xor(s, 2);
      s += __shfl_xor(s, 4); s += __shfl_xor(s, 8);
      if (lrow == 0) e_red[wm * 32 + mi * 16 + (lane >> 4) * 4 + j][wn] = s;
    }
  }
  __syncthreads();
  if (tid < 64) {
    float s = e_red[tid][0] + e_red[tid][1] + e_red[tid][2] + e_red[tid][3];
    energy[m0 + tid] = (s + vbv) * 0.04419417382415922f;  // 1/sqrt(512)
  }
}

// ---------------- kernel 4: softmax over T per batch ----------------
__global__ __launch_bounds__(256) void k_softmax(const float* __restrict__ energy,
                                                 float* __restrict__ alpha) {
  const int b = blockIdx.x, tid = threadIdx.x;
  const float* e = energy + b * T_;
  float4 v0 = ((const float4*)e)[tid * 2];
  float4 v1 = ((const float4*)e)[tid * 2 + 1];
  float m = fmaxf(fmaxf(fmaxf(v0.x, v0.y), fmaxf(v0.z, v0.w)),
                  fmaxf(fmaxf(v1.x, v1.y), fmaxf(v1.z, v1.w)));
  #pragma unroll
  for (int off = 32; off; off >>= 1) m = fmaxf(m, __shfl_xor(m, off));
  __shared__ float rmax[4], rsum[4];
  const int lane = tid & 63, wv = tid >> 6;
  if (!lane) rmax[wv] = m;
  __syncthreads();
  m = fmaxf(fmaxf(rmax[0], rmax[1]), fmaxf(rmax[2], rmax[3]));
  float x0 = expf(v0.x - m), x1 = expf(v0.y - m), x2 = expf(v0.z - m), x3 = expf(v0.w - m);
  float x4 = expf(v1.x - m), x5 = expf(v1.y - m), x6 = expf(v1.z - m), x7 = expf(v1.w - m);
  float s = ((x0 + x1) + (x2 + x3)) + ((x4 + x5) + (x6 + x7));
  #pragma unroll
  for (int off = 32; off; off >>= 1) s += __shfl_xor(s, off);
  if (!lane) rsum[wv] = s;
  __syncthreads();
  s = (rsum[0] + rsum[1]) + (rsum[2] + rsum[3]);
  float inv = 1.f / s;
  float4 o0 = {x0 * inv, x1 * inv, x2 * inv, x3 * inv};
  float4 o1 = {x4 * inv, x5 * inv, x6 * inv, x7 * inv};
  float* ao = alpha + b * T_;
  ((float4*)ao)[tid * 2] = o0;
  ((float4*)ao)[tid * 2 + 1] = o1;
}

// ---------------- kernel 5: context partials over t-chunks ----------------
__global__ __launch_bounds__(256) void k_ctx_partial(const float* __restrict__ feat,
                                                     const float* __restrict__ alpha,
                                                     float* __restrict__ part) {
  const int b = blockIdx.x, fh = blockIdx.y, tc = blockIdx.z;
  const int tid = threadIdx.x;
  __shared__ float sa[128];
  if (tid < 128) sa[tid] = alpha[b * T_ + tc * 128 + tid];
  __syncthreads();
  const int f = fh * 1024 + tid * 4;
  const float* fp = feat + ((size_t)(b * T_ + tc * 128)) * F_ + f;
  float4 s = {0.f, 0.f, 0.f, 0.f};
  #pragma unroll 4
  for (int t = 0; t < 128; ++t) {
    float a = sa[t];
    float4 v = *(const float4*)(fp + (size_t)t * F_);
    s.x += a * v.x; s.y += a * v.y; s.z += a * v.z; s.w += a * v.w;
  }
  *(float4*)(part + ((size_t)(b * 16 + tc)) * F_ + f) = s;
}

// ---------------- kernel 6: reduce partials ----------------
__global__ __launch_bounds__(256) void k_ctx_reduce(const float* __restrict__ part,
                                                    float* __restrict__ ctx) {
  const int i4 = blockIdx.x * 256 + threadIdx.x;  // float4 index, 16384 total
  const int b = i4 >> 9, f4 = i4 & 511;
  const float4* p = (const float4*)part;
  float4 s = {0.f, 0.f, 0.f, 0.f};
  #pragma unroll
  for (int tc = 0; tc < 16; ++tc) {
    float4 v = p[((b * 16 + tc) << 9) + f4];
    s.x += v.x; s.y += v.y; s.z += v.z; s.w += v.w;
  }
  ((float4*)ctx)[i4] = s;
}

extern "C" void kernel_launch(void* const* d_in, const int* in_sizes, int n_in,
                              void* d_out, int out_size, void* d_ws, size_t ws_size,
                              hipStream_t stream) {
  const float* feat   = (const float*)d_in[0];
  const float* hidden = (const float*)d_in[1];
  const float* Wh     = (const float*)d_in[2];
  const float* bh     = (const float*)d_in[3];
  const float* Wa     = (const float*)d_in[4];
  const float* ba     = (const float*)d_in[5];
  const float* vw     = (const float*)d_in[6];
  const float* vb     = (const float*)d_in[7];

  float* ctx   = (float*)d_out;            // [32][2048]
  float* alpha = (float*)d_out + B_ * T_;  // [32][2048]

  char* ws = (char*)d_ws;
  unsigned short* wab = (unsigned short*)ws;               // 2 MB bf16 W_a
  float* hcomb  = (float*)(ws + 2097152);                  // 64 KB
  float* energy = (float*)(ws + 2097152 + 65536);          // 256 KB
  float* part   = (float*)(ws + 2097152 + 65536 + 262144); // 4 MB

  k_convert_wa<<<dim3(1024), dim3(256), 0, stream>>>(Wa, wab);
  k_hproj<<<dim3(4096), dim3(256), 0, stream>>>(hidden, Wh, bh, ba, hcomb);
  k_energy<<<dim3(1024), dim3(512), 0, stream>>>(feat, wab, hcomb, vw, vb, energy);
  k_softmax<<<dim3(32), dim3(256), 0, stream>>>(energy, alpha);
  k_ctx_partial<<<dim3(32, 2, 16), dim3(256), 0, stream>>>(feat, alpha, part);
  k_ctx_reduce<<<dim3(64), dim3(256), 0, stream>>>(part, ctx);
}